// Round 6
// baseline (243.632 us; speedup 1.0000x reference)
//
#include <hip/hip_runtime.h>
#include <hip/hip_cooperative_groups.h>
#include <math.h>

namespace cg = cooperative_groups;

typedef __attribute__((ext_vector_type(8))) short s8v;   // 8 bf16 (4 VGPRs)
typedef __attribute__((ext_vector_type(4))) float f4v;   // MFMA accumulator

constexpr int E_TOTAL = 320000;
constexpr int NODE_N  = 10000;
constexpr int NODE_D  = 256;   // D (K of node GEMM)
constexpr int H       = 64;
constexpr int NC      = 128;   // node-GEMM N = 2H (P | Q)

// workspace layout (bytes)
constexpr size_t PQ_OFF = 0;          // [10000][128] bf16 = 2,560,000 B
constexpr size_t WT_OFF = 2560000;    // W'^T bf16 [128][256] = 64 KB

__device__ __forceinline__ unsigned short f2bf(float f) {
    unsigned u = __float_as_uint(f);
    u += 0x7fffu + ((u >> 16) & 1u);   // RNE
    return (unsigned short)(u >> 16);
}

// sigmoid((la + log u - log1p(-u))/0.1) = 1 / (1 + e^{-10 la} * ((1-u)/u)^10)
// r^10 saturation (inf/0) yields the correct gate limits (0/1); exp(-10la)
// never underflows to 0 for |la|<~80, so no inf*0 NaN.
__device__ __forceinline__ float fast_gate(float la, float u) {
    float r  = (1.0f - u) * __builtin_amdgcn_rcpf(u);
    float r2 = r * r, r4 = r2 * r2, r8 = r4 * r4;
    float t  = __expf(-10.0f * la) * (r8 * r2);
    return 1.0f / (1.0f + t);
}

// ---------------- single cooperative kernel: wprep+wgate | node GEMM | edge pass
__global__ __launch_bounds__(256, 4)
void fused_all(const float* __restrict__ x,
               const int*   __restrict__ eidx,
               const float* __restrict__ la,
               const float* __restrict__ W1,
               const float* __restrict__ b1,
               const float* __restrict__ W2,
               const float* __restrict__ b2,
               const float* __restrict__ wla1,
               const float* __restrict__ wla2,
               const float* __restrict__ ue,
               const float* __restrict__ u1,
               const float* __restrict__ u2,
               float* __restrict__ out,
               unsigned short* __restrict__ pq,
               unsigned short* __restrict__ wt)
{
    cg::grid_group grid = cg::this_grid();
    const int t   = threadIdx.x;
    const int bid = blockIdx.x;

    // ================= phase 0: W'^T image (blocks 0..15) | weight gates (16..399)
    if (bid < 16) {
        int tid = bid * 256 + t;                        // 0..4095
        int c  = tid >> 5;                              // col 0..127
        int g  = tid & 31;                              // 16B granule (8 k's)
        int k0 = g * 8;
        unsigned short r[8];
        #pragma unroll
        for (int q = 0; q < 8; ++q) {
            int k = k0 + q;
            float v = (c < 64) ? W1[(size_t)k * H + c] : W1[(size_t)(256 + k) * H + (c - 64)];
            r[q] = f2bf(v);
        }
        *(uint4*)(wt + (size_t)c * 256 + k0) = *(const uint4*)r;
    } else if (bid < 400) {
        int tid = (bid - 16) * 256 + t;                 // 0..98303
        const float4* la4; const float4* u4; float4* o4; int idx;
        if (tid < 65536) { la4 = (const float4*)wla1; u4 = (const float4*)u1; o4 = (float4*)(out + 320000); idx = tid; }
        else             { la4 = (const float4*)wla2; u4 = (const float4*)u2; o4 = (float4*)(out + 582144); idx = tid - 65536; }
        float4 lav = la4[idx], uv = u4[idx], rr;
        rr.x = fast_gate(lav.x, uv.x);
        rr.y = fast_gate(lav.y, uv.y);
        rr.z = fast_gate(lav.z, uv.z);
        rr.w = fast_gate(lav.w, uv.w);
        o4[idx] = rr;
    }

    __threadfence();          // device-scope release: wt visible across XCDs
    grid.sync();

    // ================= phase 1: node GEMM C[10000][128] = x @ [W1a|W1b] -> bf16 pq
    if (bid < 313) {
        const int lane = t & 63;
        const int w    = t >> 6;
        const int cg_  = lane & 15;
        const int rg   = lane >> 4;
        const int mw   = w >> 1;
        const int nw   = w & 1;
        const int rowBase = bid * 32 + mw * 16;

        int arow = rowBase + cg_;
        if (arow > NODE_N - 1) arow = NODE_N - 1;
        const float* xr = x + (size_t)arow * NODE_D + rg * 8;
        const unsigned short* wbase = wt + (size_t)(nw * 64 + cg_) * 256 + rg * 8;

        f4v acc[4] = {};
        #pragma unroll
        for (int ks = 0; ks < 8; ++ks) {
            float4 u0v = *(const float4*)(xr + ks * 32);
            float4 u1v = *(const float4*)(xr + ks * 32 + 4);
            unsigned short rr[8] = { f2bf(u0v.x), f2bf(u0v.y), f2bf(u0v.z), f2bf(u0v.w),
                                     f2bf(u1v.x), f2bf(u1v.y), f2bf(u1v.z), f2bf(u1v.w) };
            s8v af = *(const s8v*)rr;
            #pragma unroll
            for (int bc = 0; bc < 4; ++bc) {
                s8v bf = *(const s8v*)(wbase + (size_t)bc * 16 * 256 + ks * 32);
                acc[bc] = __builtin_amdgcn_mfma_f32_16x16x32_bf16(af, bf, acc[bc], 0, 0, 0);
            }
        }
        #pragma unroll
        for (int reg = 0; reg < 4; ++reg) {
            int row = rowBase + rg * 4 + reg;
            if (row < NODE_N) {
                #pragma unroll
                for (int bc = 0; bc < 4; ++bc)
                    pq[(size_t)row * NC + nw * 64 + bc * 16 + cg_] = f2bf(acc[bc][reg]);
            }
        }
    }

    __threadfence();          // pq visible across XCDs
    grid.sync();

    // ================= phase 2: edges, 64/chunk, grid-stride
    {
        const int q = t & 3;
        const int esub = t >> 2;

        float bb[16], ww[16];
        #pragma unroll
        for (int m = 0; m < 4; ++m) {
            *(float4*)&bb[4 * m] = *(const float4*)(b1 + q * 16 + 4 * m);
            *(float4*)&ww[4 * m] = *(const float4*)(W2 + q * 16 + 4 * m);
        }
        const float bias2 = b2[0];

        for (int c = bid; c < E_TOTAL / 64; c += gridDim.x) {
            const int e = c * 64 + esub;
            const int i = eidx[e];
            const int j = eidx[E_TOTAL + e];

            const uint4* Pp = (const uint4*)(pq + (size_t)i * NC + q * 16);
            const uint4* Qp = (const uint4*)(pq + (size_t)j * NC + 64 + q * 16);
            uint4 p0 = Pp[0], p1 = Pp[1];
            uint4 q0 = Qp[0], q1 = Qp[1];

            unsigned P8[8] = { p0.x, p0.y, p0.z, p0.w, p1.x, p1.y, p1.z, p1.w };
            unsigned Q8[8] = { q0.x, q0.y, q0.z, q0.w, q1.x, q1.y, q1.z, q1.w };

            float s = 0.0f;
            #pragma unroll
            for (int m = 0; m < 8; ++m) {
                float pl = __uint_as_float(P8[m] << 16);
                float ph = __uint_as_float(P8[m] & 0xffff0000u);
                float ql = __uint_as_float(Q8[m] << 16);
                float qh = __uint_as_float(Q8[m] & 0xffff0000u);
                float h0 = fmaxf(pl + ql + bb[2 * m], 0.0f);
                float h1 = fmaxf(ph + qh + bb[2 * m + 1], 0.0f);
                s = fmaf(h0, ww[2 * m], s);
                s = fmaf(h1, ww[2 * m + 1], s);
            }
            s += __shfl_xor(s, 1);
            s += __shfl_xor(s, 2);

            if (q == 0) {
                out[e] = (s + bias2) * fast_gate(la[e], ue[e]);
            }
        }
    }
}

extern "C" void kernel_launch(void* const* d_in, const int* in_sizes, int n_in,
                              void* d_out, int out_size, void* d_ws, size_t ws_size,
                              hipStream_t stream) {
    const float* x    = (const float*)d_in[0];
    const int*   ei   = (const int*)  d_in[1];
    const float* la   = (const float*)d_in[2];
    const float* W1   = (const float*)d_in[3];
    const float* b1   = (const float*)d_in[4];
    const float* W2   = (const float*)d_in[5];
    const float* b2   = (const float*)d_in[6];
    const float* wla1 = (const float*)d_in[7];
    const float* wla2 = (const float*)d_in[8];
    const float* ue   = (const float*)d_in[9];
    const float* u1   = (const float*)d_in[10];
    const float* u2   = (const float*)d_in[11];
    float* out = (float*)d_out;
    char*  ws  = (char*)d_ws;

    unsigned short* pq = (unsigned short*)(ws + PQ_OFF);
    unsigned short* wt = (unsigned short*)(ws + WT_OFF);

    void* args[] = { (void*)&x, (void*)&ei, (void*)&la, (void*)&W1, (void*)&b1,
                     (void*)&W2, (void*)&b2, (void*)&wla1, (void*)&wla2,
                     (void*)&ue, (void*)&u1, (void*)&u2,
                     (void*)&out, (void*)&pq, (void*)&wt };
    hipLaunchCooperativeKernel((const void*)fused_all, dim3(512), dim3(256),
                               args, 0, stream);
}

// Round 7
// 126.880 us; speedup vs baseline: 1.9202x; 1.9202x over previous
//
#include <hip/hip_runtime.h>
#include <math.h>

typedef __attribute__((ext_vector_type(8))) short s8v;   // 8 bf16 (4 VGPRs)
typedef __attribute__((ext_vector_type(4))) float f4v;   // MFMA accumulator

constexpr int E_TOTAL = 320000;
constexpr int NODE_N  = 10000;
constexpr int NODE_D  = 256;   // D (K of node GEMM)
constexpr int NC      = 128;   // node-GEMM N = 2H (P | Q)
constexpr int GRID    = 512;

// workspace layout (bytes)
constexpr size_t PQ_OFF  = 0;          // [10000][128] bf16 = 2,560,000 B
constexpr size_t BAR_OFF = 3145728;    // barrier counter (zeroed per call)

__device__ __forceinline__ unsigned short f2bf(float f) {
    unsigned u = __float_as_uint(f);
    u += 0x7fffu + ((u >> 16) & 1u);   // RNE
    return (unsigned short)(u >> 16);
}

// sigmoid((la + log u - log1p(-u))/0.1) = 1 / (1 + e^{-10 la} * ((1-u)/u)^10)
__device__ __forceinline__ float fast_gate(float la, float u) {
    float r  = (1.0f - u) * __builtin_amdgcn_rcpf(u);
    float r2 = r * r, r4 = r2 * r2, r8 = r4 * r4;
    float t  = __expf(-10.0f * la) * (r8 * r2);
    return 1.0f / (1.0f + t);
}

// ---------------- single kernel: {node GEMM | wgate} -> device barrier -> edges
__global__ __launch_bounds__(256, 4)
void fused_all(const float* __restrict__ x,
               const int*   __restrict__ eidx,
               const float* __restrict__ la,
               const float* __restrict__ W1,
               const float* __restrict__ b1,
               const float* __restrict__ W2,
               const float* __restrict__ b2,
               const float* __restrict__ wla1,
               const float* __restrict__ wla2,
               const float* __restrict__ ue,
               const float* __restrict__ u1,
               const float* __restrict__ u2,
               float* __restrict__ out,
               unsigned short* __restrict__ pq,
               unsigned* __restrict__ bar)
{
    const int t   = threadIdx.x;
    const int bid = blockIdx.x;

    // ================= phase A
    if (bid < 313) {
        // ---- node GEMM: C[10000][128] = x @ [W1a|W1b] -> bf16 pq
        // W' col c, k: c<64 ? W1[k][c] : W1[256+k][c-64]; B-frags read fp32 -> bf16 inline.
        const int lane = t & 63;
        const int w    = t >> 6;
        const int cg_  = lane & 15;
        const int rg   = lane >> 4;
        const int mw   = w >> 1;
        const int nw   = w & 1;
        const int rowBase = bid * 32 + mw * 16;

        int arow = rowBase + cg_;
        if (arow > NODE_N - 1) arow = NODE_N - 1;
        const float* xr = x + (size_t)arow * NODE_D + rg * 8;
        const float* wB = W1 + (nw ? (size_t)256 * 64 : 0) + (size_t)rg * 8 * 64 + cg_;

        f4v acc[4] = {};
        #pragma unroll
        for (int ks = 0; ks < 8; ++ks) {
            float4 u0v = *(const float4*)(xr + ks * 32);
            float4 u1v = *(const float4*)(xr + ks * 32 + 4);
            unsigned short ra[8] = { f2bf(u0v.x), f2bf(u0v.y), f2bf(u0v.z), f2bf(u0v.w),
                                     f2bf(u1v.x), f2bf(u1v.y), f2bf(u1v.z), f2bf(u1v.w) };
            s8v af = *(const s8v*)ra;
            const float* bk = wB + (size_t)ks * 32 * 64;
            #pragma unroll
            for (int bc = 0; bc < 4; ++bc) {
                const float* bp = bk + bc * 16;
                unsigned short rb[8];
                #pragma unroll
                for (int q = 0; q < 8; ++q)
                    rb[q] = f2bf(bp[(size_t)q * 64]);
                s8v bf = *(const s8v*)rb;
                acc[bc] = __builtin_amdgcn_mfma_f32_16x16x32_bf16(af, bf, acc[bc], 0, 0, 0);
            }
        }
        #pragma unroll
        for (int reg = 0; reg < 4; ++reg) {
            int row = rowBase + rg * 4 + reg;
            if (row < NODE_N) {
                #pragma unroll
                for (int bc = 0; bc < 4; ++bc)
                    pq[(size_t)row * NC + nw * 64 + bc * 16 + cg_] = f2bf(acc[bc][reg]);
            }
        }
    } else {
        // ---- weight gates: 199 blocks, grid-stride over 98304 float4 items
        for (int idx = (bid - 313) * 256 + t; idx < 98304; idx += 199 * 256) {
            const float4* la4; const float4* u4; float4* o4; int k;
            if (idx < 65536) { la4 = (const float4*)wla1; u4 = (const float4*)u1; o4 = (float4*)(out + 320000); k = idx; }
            else             { la4 = (const float4*)wla2; u4 = (const float4*)u2; o4 = (float4*)(out + 582144); k = idx - 65536; }
            float4 lav = la4[k], uv = u4[k], rr;
            rr.x = fast_gate(lav.x, uv.x);
            rr.y = fast_gate(lav.y, uv.y);
            rr.z = fast_gate(lav.z, uv.z);
            rr.w = fast_gate(lav.w, uv.w);
            o4[k] = rr;
        }
    }

    // ================= device barrier (G16: device-scope fence + atomics)
    __syncthreads();
    if (t == 0) {
        __threadfence();                           // release: pq -> visible device-wide
        atomicAdd(bar, 1u);
        while (atomicAdd(bar, 0u) < (unsigned)GRID)
            __builtin_amdgcn_s_sleep(8);
    }
    __syncthreads();
    __threadfence();                               // acquire side

    // ================= phase B: edges, 64 per chunk, grid-stride
    {
        const int q = t & 3;
        const int esub = t >> 2;

        float bb[16], ww[16];
        #pragma unroll
        for (int m = 0; m < 4; ++m) {
            *(float4*)&bb[4 * m] = *(const float4*)(b1 + q * 16 + 4 * m);
            *(float4*)&ww[4 * m] = *(const float4*)(W2 + q * 16 + 4 * m);
        }
        const float bias2 = b2[0];

        for (int c = bid; c < E_TOTAL / 64; c += GRID) {
            const int e = c * 64 + esub;
            const int i = eidx[e];
            const int j = eidx[E_TOTAL + e];

            const uint4* Pp = (const uint4*)(pq + (size_t)i * NC + q * 16);
            const uint4* Qp = (const uint4*)(pq + (size_t)j * NC + 64 + q * 16);
            uint4 p0 = Pp[0], p1 = Pp[1];
            uint4 q0 = Qp[0], q1 = Qp[1];

            unsigned P8[8] = { p0.x, p0.y, p0.z, p0.w, p1.x, p1.y, p1.z, p1.w };
            unsigned Q8[8] = { q0.x, q0.y, q0.z, q0.w, q1.x, q1.y, q1.z, q1.w };

            float s = 0.0f;
            #pragma unroll
            for (int m = 0; m < 8; ++m) {
                float pl = __uint_as_float(P8[m] << 16);
                float ph = __uint_as_float(P8[m] & 0xffff0000u);
                float ql = __uint_as_float(Q8[m] << 16);
                float qh = __uint_as_float(Q8[m] & 0xffff0000u);
                float h0 = fmaxf(pl + ql + bb[2 * m], 0.0f);
                float h1 = fmaxf(ph + qh + bb[2 * m + 1], 0.0f);
                s = fmaf(h0, ww[2 * m], s);
                s = fmaf(h1, ww[2 * m + 1], s);
            }
            s += __shfl_xor(s, 1);
            s += __shfl_xor(s, 2);

            if (q == 0)
                out[e] = (s + bias2) * fast_gate(la[e], ue[e]);
        }
    }
}

extern "C" void kernel_launch(void* const* d_in, const int* in_sizes, int n_in,
                              void* d_out, int out_size, void* d_ws, size_t ws_size,
                              hipStream_t stream) {
    const float* x    = (const float*)d_in[0];
    const int*   ei   = (const int*)  d_in[1];
    const float* la   = (const float*)d_in[2];
    const float* W1   = (const float*)d_in[3];
    const float* b1   = (const float*)d_in[4];
    const float* W2   = (const float*)d_in[5];
    const float* b2   = (const float*)d_in[6];
    const float* wla1 = (const float*)d_in[7];
    const float* wla2 = (const float*)d_in[8];
    const float* ue   = (const float*)d_in[9];
    const float* u1   = (const float*)d_in[10];
    const float* u2   = (const float*)d_in[11];
    float* out = (float*)d_out;
    char*  ws  = (char*)d_ws;

    unsigned short* pq  = (unsigned short*)(ws + PQ_OFF);
    unsigned*       bar = (unsigned*)(ws + BAR_OFF);

    hipMemsetAsync(bar, 0, 64, stream);   // reset barrier counter every call

    void* args[] = { (void*)&x, (void*)&ei, (void*)&la, (void*)&W1, (void*)&b1,
                     (void*)&W2, (void*)&b2, (void*)&wla1, (void*)&wla2,
                     (void*)&ue, (void*)&u1, (void*)&u2,
                     (void*)&out, (void*)&pq, (void*)&bar };
    hipLaunchCooperativeKernel((const void*)fused_all, dim3(GRID), dim3(256),
                               args, 0, stream);
}

// Round 8
// 31.346 us; speedup vs baseline: 7.7723x; 4.0477x over previous
//
#include <hip/hip_runtime.h>
#include <math.h>

typedef __attribute__((ext_vector_type(8))) short s8v;   // 8 bf16 (4 VGPRs)
typedef __attribute__((ext_vector_type(4))) float f4v;   // MFMA accumulator

constexpr int E_TOTAL = 320000;
constexpr int NODE_N  = 10000;
constexpr int NODE_D  = 256;   // D (K of node GEMM)
constexpr int NC      = 128;   // node-GEMM N = 2H (P | Q)

// workspace layout (bytes)
constexpr size_t PQ_OFF = 0;   // [10000][128] bf16 = 2,560,000 B

__device__ __forceinline__ unsigned short f2bf(float f) {
    unsigned u = __float_as_uint(f);
    u += 0x7fffu + ((u >> 16) & 1u);   // RNE
    return (unsigned short)(u >> 16);
}

// sigmoid((la + log u - log1p(-u))/0.1) = 1 / (1 + e^{-10 la} * ((1-u)/u)^10)
// r^10 saturation (inf/0) gives the correct 0/1 gate limits.
__device__ __forceinline__ float fast_gate(float la, float u) {
    float r  = (1.0f - u) * __builtin_amdgcn_rcpf(u);
    float r2 = r * r, r4 = r2 * r2, r8 = r4 * r4;
    float t  = __expf(-10.0f * la) * (r8 * r2);
    return 1.0f / (1.0f + t);
}

// ---------------- K1: node GEMM (blocks 0..312) | weight gates (blocks 313..511)
// node GEMM: C[10000][128] = x @ [W1a|W1b] -> bf16 pq. W' col c,k:
// c<64 ? W1[k][c] : W1[256+k][c-64]; B-frags read fp32 global->reg, cvt inline (L2-hot).
__global__ __launch_bounds__(256, 4)
void k1_node_wgate(const float* __restrict__ x,
                   const float* __restrict__ W1,
                   const float* __restrict__ wla1,
                   const float* __restrict__ wla2,
                   const float* __restrict__ u1,
                   const float* __restrict__ u2,
                   float* __restrict__ out,
                   unsigned short* __restrict__ pq)
{
    const int t   = threadIdx.x;
    const int bid = blockIdx.x;

    if (bid < 313) {
        const int lane = t & 63;
        const int w    = t >> 6;
        const int cg_  = lane & 15;
        const int rg   = lane >> 4;
        const int mw   = w >> 1;
        const int nw   = w & 1;
        const int rowBase = bid * 32 + mw * 16;

        int arow = rowBase + cg_;
        if (arow > NODE_N - 1) arow = NODE_N - 1;
        const float* xr = x + (size_t)arow * NODE_D + rg * 8;
        const float* wB = W1 + (nw ? (size_t)256 * 64 : 0) + (size_t)rg * 8 * 64 + cg_;

        f4v acc[4] = {};
        #pragma unroll
        for (int ks = 0; ks < 8; ++ks) {
            float4 u0v = *(const float4*)(xr + ks * 32);
            float4 u1v = *(const float4*)(xr + ks * 32 + 4);
            unsigned short ra[8] = { f2bf(u0v.x), f2bf(u0v.y), f2bf(u0v.z), f2bf(u0v.w),
                                     f2bf(u1v.x), f2bf(u1v.y), f2bf(u1v.z), f2bf(u1v.w) };
            s8v af = *(const s8v*)ra;
            const float* bk = wB + (size_t)ks * 32 * 64;
            #pragma unroll
            for (int bc = 0; bc < 4; ++bc) {
                const float* bp = bk + bc * 16;
                unsigned short rb[8];
                #pragma unroll
                for (int q = 0; q < 8; ++q)
                    rb[q] = f2bf(bp[(size_t)q * 64]);
                s8v bf = *(const s8v*)rb;
                acc[bc] = __builtin_amdgcn_mfma_f32_16x16x32_bf16(af, bf, acc[bc], 0, 0, 0);
            }
        }
        #pragma unroll
        for (int reg = 0; reg < 4; ++reg) {
            int row = rowBase + rg * 4 + reg;
            if (row < NODE_N) {
                #pragma unroll
                for (int bc = 0; bc < 4; ++bc)
                    pq[(size_t)row * NC + nw * 64 + bc * 16 + cg_] = f2bf(acc[bc][reg]);
            }
        }
    } else {
        // weight gates: 199 blocks grid-stride over 98304 float4 items
        for (int idx = (bid - 313) * 256 + t; idx < 98304; idx += 199 * 256) {
            const float4* la4; const float4* u4; float4* o4; int k;
            if (idx < 65536) { la4 = (const float4*)wla1; u4 = (const float4*)u1; o4 = (float4*)(out + 320000); k = idx; }
            else             { la4 = (const float4*)wla2; u4 = (const float4*)u2; o4 = (float4*)(out + 582144); k = idx - 65536; }
            float4 lav = la4[k], uv = u4[k], rr;
            rr.x = fast_gate(lav.x, uv.x);
            rr.y = fast_gate(lav.y, uv.y);
            rr.z = fast_gate(lav.z, uv.z);
            rr.w = fast_gate(lav.w, uv.w);
            o4[k] = rr;
        }
    }
}

// ---------------- K2: edge pass. out[e] = (sum_c relu(P[i][c]+Q[j][c]+b1[c])*W2[c]+b2)*gate
// 4 lanes per edge (16 cols each); 64 edges per 256-thread block; PQ is L2-resident.
__global__ __launch_bounds__(256, 4)
void k2_edge(const unsigned short* __restrict__ pq,
             const int*   __restrict__ eidx,
             const float* __restrict__ la,
             const float* __restrict__ b1,
             const float* __restrict__ W2,
             const float* __restrict__ b2,
             const float* __restrict__ ue,
             float* __restrict__ out)
{
    const int t = threadIdx.x;
    const int q = t & 3;
    const int e = blockIdx.x * 64 + (t >> 2);

    const int i = eidx[e];
    const int j = eidx[E_TOTAL + e];

    const uint4* Pp = (const uint4*)(pq + (size_t)i * NC + q * 16);
    const uint4* Qp = (const uint4*)(pq + (size_t)j * NC + 64 + q * 16);
    uint4 p0 = Pp[0], p1 = Pp[1];
    uint4 q0 = Qp[0], q1 = Qp[1];

    float bb[16], ww[16];
    #pragma unroll
    for (int m = 0; m < 4; ++m) {
        *(float4*)&bb[4 * m] = *(const float4*)(b1 + q * 16 + 4 * m);
        *(float4*)&ww[4 * m] = *(const float4*)(W2 + q * 16 + 4 * m);
    }

    unsigned P8[8] = { p0.x, p0.y, p0.z, p0.w, p1.x, p1.y, p1.z, p1.w };
    unsigned Q8[8] = { q0.x, q0.y, q0.z, q0.w, q1.x, q1.y, q1.z, q1.w };

    float s = 0.0f;
    #pragma unroll
    for (int m = 0; m < 8; ++m) {
        float pl = __uint_as_float(P8[m] << 16);
        float ph = __uint_as_float(P8[m] & 0xffff0000u);
        float ql = __uint_as_float(Q8[m] << 16);
        float qh = __uint_as_float(Q8[m] & 0xffff0000u);
        float h0 = fmaxf(pl + ql + bb[2 * m], 0.0f);
        float h1 = fmaxf(ph + qh + bb[2 * m + 1], 0.0f);
        s = fmaf(h0, ww[2 * m], s);
        s = fmaf(h1, ww[2 * m + 1], s);
    }
    s += __shfl_xor(s, 1);
    s += __shfl_xor(s, 2);

    if (q == 0) {
        out[e] = (s + b2[0]) * fast_gate(la[e], ue[e]);
    }
}

extern "C" void kernel_launch(void* const* d_in, const int* in_sizes, int n_in,
                              void* d_out, int out_size, void* d_ws, size_t ws_size,
                              hipStream_t stream) {
    const float* x    = (const float*)d_in[0];
    const int*   ei   = (const int*)  d_in[1];
    const float* la   = (const float*)d_in[2];
    const float* W1   = (const float*)d_in[3];
    const float* b1   = (const float*)d_in[4];
    const float* W2   = (const float*)d_in[5];
    const float* b2   = (const float*)d_in[6];
    const float* wla1 = (const float*)d_in[7];
    const float* wla2 = (const float*)d_in[8];
    const float* ue   = (const float*)d_in[9];
    const float* u1   = (const float*)d_in[10];
    const float* u2   = (const float*)d_in[11];
    float* out = (float*)d_out;
    char*  ws  = (char*)d_ws;

    unsigned short* pq = (unsigned short*)(ws + PQ_OFF);

    hipLaunchKernelGGL(k1_node_wgate, dim3(512), dim3(256), 0, stream,
                       x, W1, wla1, wla2, u1, u2, out, pq);
    hipLaunchKernelGGL(k2_edge, dim3(E_TOTAL / 64), dim3(256), 0, stream,
                       pq, ei, la, b1, W2, b2, ue, out);
}